// Round 4
// baseline (656.783 us; speedup 1.0000x reference)
//
#include <hip/hip_runtime.h>
#include <stdint.h>

#define NTAGS 256
#define BATCH 64
#define SEQ   512

#if __has_builtin(__builtin_amdgcn_fdot2_f32_bf16)
#define HAVE_DOT2_BF16 1
typedef __bf16 bf16x2_t __attribute__((ext_vector_type(2)));
#define BCAST(x) __builtin_bit_cast(bf16x2_t, (unsigned int)(x))
#endif

// ---------------- wave (64-lane) reductions ----------------
__device__ __forceinline__ float wave_max(float v) {
#pragma unroll
  for (int o = 32; o; o >>= 1) v = fmaxf(v, __shfl_xor(v, o));
  return v;
}
__device__ __forceinline__ float wave_sum(float v) {
#pragma unroll
  for (int o = 32; o; o >>= 1) v += __shfl_xor(v, o);
  return v;
}

// f32 -> bf16 bits, round-to-nearest-even
__device__ __forceinline__ unsigned int f32_to_bf16_bits(float f) {
  unsigned int u = __float_as_uint(f);
  return (u + 0x7FFFu + ((u >> 16) & 1u)) >> 16;
}

// 128 packed-bf16x2 ET values. Rounds 1-3 all silently spilled these to
// scratch: VGPR_Count=84 == 512-reg file / 6-waves-per-EU RA budget. The fix
// is amdgpu_waves_per_eu(1,1) on the kernel (below), which raises the RA
// ceiling to the full register file; the named locals are kept so no scratch
// array can ever form.
#define ET_ALL(M) \
  M(0) M(1) M(2) M(3) M(4) M(5) M(6) M(7) \
  M(8) M(9) M(10) M(11) M(12) M(13) M(14) M(15) \
  M(16) M(17) M(18) M(19) M(20) M(21) M(22) M(23) \
  M(24) M(25) M(26) M(27) M(28) M(29) M(30) M(31) \
  M(32) M(33) M(34) M(35) M(36) M(37) M(38) M(39) \
  M(40) M(41) M(42) M(43) M(44) M(45) M(46) M(47) \
  M(48) M(49) M(50) M(51) M(52) M(53) M(54) M(55) \
  M(56) M(57) M(58) M(59) M(60) M(61) M(62) M(63) \
  M(64) M(65) M(66) M(67) M(68) M(69) M(70) M(71) \
  M(72) M(73) M(74) M(75) M(76) M(77) M(78) M(79) \
  M(80) M(81) M(82) M(83) M(84) M(85) M(86) M(87) \
  M(88) M(89) M(90) M(91) M(92) M(93) M(94) M(95) \
  M(96) M(97) M(98) M(99) M(100) M(101) M(102) M(103) \
  M(104) M(105) M(106) M(107) M(108) M(109) M(110) M(111) \
  M(112) M(113) M(114) M(115) M(116) M(117) M(118) M(119) \
  M(120) M(121) M(122) M(123) M(124) M(125) M(126) M(127)

// 64 lines; (i, j=i+64, chain_a, chain_b). 8 acc chains -> dependent reuse of a
// chain is >= 8 instructions apart (covers ~4-cyc VALU dependency latency).
#define DOT_ALL(M) \
  M(0,64,0,1) M(1,65,2,3) M(2,66,4,5) M(3,67,6,7) \
  M(4,68,0,1) M(5,69,2,3) M(6,70,4,5) M(7,71,6,7) \
  M(8,72,0,1) M(9,73,2,3) M(10,74,4,5) M(11,75,6,7) \
  M(12,76,0,1) M(13,77,2,3) M(14,78,4,5) M(15,79,6,7) \
  M(16,80,0,1) M(17,81,2,3) M(18,82,4,5) M(19,83,6,7) \
  M(20,84,0,1) M(21,85,2,3) M(22,86,4,5) M(23,87,6,7) \
  M(24,88,0,1) M(25,89,2,3) M(26,90,4,5) M(27,91,6,7) \
  M(28,92,0,1) M(29,93,2,3) M(30,94,4,5) M(31,95,6,7) \
  M(32,96,0,1) M(33,97,2,3) M(34,98,4,5) M(35,99,6,7) \
  M(36,100,0,1) M(37,101,2,3) M(38,102,4,5) M(39,103,6,7) \
  M(40,104,0,1) M(41,105,2,3) M(42,106,4,5) M(43,107,6,7) \
  M(44,108,0,1) M(45,109,2,3) M(46,110,4,5) M(47,111,6,7) \
  M(48,112,0,1) M(49,113,2,3) M(50,114,4,5) M(51,115,6,7) \
  M(52,116,0,1) M(53,117,2,3) M(54,118,4,5) M(55,119,6,7) \
  M(56,120,0,1) M(57,121,2,3) M(58,122,4,5) M(59,123,6,7) \
  M(60,124,0,1) M(61,125,2,3) M(62,126,4,5) M(63,127,6,7)

#define ET_DECL(i) unsigned int et##i;
#define ET_INIT(i) \
  et##i = f32_to_bf16_bits(exp2f(trans[(2*(i))*NTAGS + k] * LOG2E)) | \
          (f32_to_bf16_bits(exp2f(trans[(2*(i)+1)*NTAGS + k] * LOG2E)) << 16);

#if HAVE_DOT2_BF16
#define DOT_STEP(i, j, ca, cb) { \
    int sa_ = __builtin_amdgcn_readlane(w0, i); \
    acc##ca = __builtin_amdgcn_fdot2_f32_bf16(BCAST(et##i), BCAST(sa_), acc##ca, false); \
    int sb_ = __builtin_amdgcn_readlane(w1, i); \
    acc##cb = __builtin_amdgcn_fdot2_f32_bf16(BCAST(et##j), BCAST(sb_), acc##cb, false); }
#else
#define DOT_STEP(i, j, ca, cb) { \
    unsigned int sa_ = (unsigned int)__builtin_amdgcn_readlane(w0, i); \
    acc##ca = fmaf(__uint_as_float(sa_ << 16),        __uint_as_float(et##i << 16),        acc##ca); \
    acc##cb = fmaf(__uint_as_float(sa_ & 0xFFFF0000u), __uint_as_float(et##i & 0xFFFF0000u), acc##cb); \
    unsigned int sb_ = (unsigned int)__builtin_amdgcn_readlane(w1, i); \
    acc##ca = fmaf(__uint_as_float(sb_ << 16),        __uint_as_float(et##j << 16),        acc##ca); \
    acc##cb = fmaf(__uint_as_float(sb_ & 0xFFFF0000u), __uint_as_float(et##j & 0xFFFF0000u), acc##cb); }
#endif

// One block per batch element. Thread k owns output tag k.
// Linear-domain forward recursion: a <- (ET^T a) * exp(logit_t), alpha
// broadcast lane->SGPR via v_readlane, exact power-of-2 renorm every 4 steps.
// amdgpu_waves_per_eu(1,1): launch is genuinely 1 wave/SIMD (64 blocks x 4
// waves on 256 CUs); this lifts the RA's VGPR budget to the full file so the
// 128 ET words stay resident (rounds 1-3 spilled them -> scratch-bound).
__global__ __launch_bounds__(256, 1) __attribute__((amdgpu_waves_per_eu(1, 1)))
void crf_fwd(const float* __restrict__ logits,
             const int*   __restrict__ tags,
             const int*   __restrict__ mask,
             const float* __restrict__ trans,
             float* __restrict__ out)
{
  const int b    = blockIdx.x;
  const int k    = threadIdx.x;
  const int wid  = k >> 6;
  const int lane = k & 63;

  __shared__ unsigned int abuf[2][NTAGS / 2];  // alpha, packed bf16x2, double-buffered
  __shared__ float red[4];
  __shared__ float rnum[4], rms[4];

  const float LOG2E = 1.4426950408889634f;
  const float LN2   = 0.6931471805599453f;

  const float* lg = logits + (size_t)b * SEQ * NTAGS;
  const int*   tg = tags + b * SEQ;
  const int*   mk = mask + b * SEQ;

  // ---------------- numerator (joint likelihood) ----------------
  float numer = 0.f, msum = 0.f;
  for (int t = k; t < SEQ; t += 256) {
    int   tag_t = tg[t];
    float m_t   = (float)mk[t];
    msum += m_t;
    if (t < SEQ - 1) {
      numer += lg[t * NTAGS + tag_t] * m_t;                       // emit, mask[:, :-1]
      numer += trans[tag_t * NTAGS + tg[t + 1]] * (float)mk[t+1]; // trans, mask[:, 1:]
    }
  }
  numer = wave_sum(numer);
  msum  = wave_sum(msum);
  if (lane == 0) { rnum[wid] = numer; rms[wid] = msum; }
  __syncthreads();
  const float numer_tot = (rnum[0] + rnum[1]) + (rnum[2] + rnum[3]);
  const float msum_tot  = (rms[0]  + rms[1])  + (rms[2]  + rms[3]);
  __syncthreads();

  // ---------------- ET column k -> 128 named registers ----------------
  ET_ALL(ET_DECL)
  ET_ALL(ET_INIT)

  // ---------------- init alpha at t=0 ----------------
  float mya = exp2f(lg[k] * LOG2E);
  int esum = 0;
  ((unsigned short*)abuf[0])[k] = (unsigned short)f32_to_bf16_bits(mya);
  __syncthreads();

  // prefetch logits/mask two steps ahead
  float g0 = lg[1 * NTAGS + k];
  float g1 = lg[2 * NTAGS + k];
  int   m0v = mk[1];
  int   m1v = mk[2];

  int cur = 0;
  for (int t = 1; t < SEQ; ++t) {
    const float g = g0;  const int m = m0v;
    g0 = g1; m0v = m1v;
    const int tpre = (t + 2 <= SEQ - 1) ? (t + 2) : (SEQ - 1);
    g1 = lg[tpre * NTAGS + k];
    m1v = mk[tpre];

    // each lane loads 2 packed-bf16 alpha words (stride-1 u32, conflict-free)
    const int w0 = (int)abuf[cur][lane];
    const int w1 = (int)abuf[cur][64 + lane];

    float acc0 = 0.f, acc1 = 0.f, acc2 = 0.f, acc3 = 0.f;
    float acc4 = 0.f, acc5 = 0.f, acc6 = 0.f, acc7 = 0.f;
    DOT_ALL(DOT_STEP)

    const float s = ((acc0 + acc1) + (acc2 + acc3)) + ((acc4 + acc5) + (acc6 + acc7));
    const float cand = s * exp2f(g * LOG2E);
    mya = m ? cand : mya;   // mask: freeze alpha when mask==0 (block-uniform)

    if ((t & 3) == 3) {
      // exact power-of-2 renorm every 4 steps; exponent bookkeeping in esum
      float mx = wave_max(mya);
      if (lane == 0) red[wid] = mx;
      __syncthreads();
      mx = fmaxf(fmaxf(red[0], red[1]), fmaxf(red[2], red[3]));
      const int e = (int)((__float_as_uint(mx) >> 23) & 0xFF) - 127;
      mya *= __uint_as_float((uint32_t)(127 - e) << 23);  // *2^-e, exact
      esum += e;
    }

    cur ^= 1;
    ((unsigned short*)abuf[cur])[k] = (unsigned short)f32_to_bf16_bits(mya);
    __syncthreads();
  }

  // ---------------- log_den = log(sum_k a) + esum*ln2 ----------------
  float ssum = wave_sum(mya);
  if (lane == 0) red[wid] = ssum;
  __syncthreads();
  ssum = (red[0] + red[1]) + (red[2] + red[3]);

  if (k == 0) {
    const float log_den = logf(ssum) + (float)esum * LN2;
    int last_idx = (int)msum_tot - 1;
    if (last_idx < 0) last_idx = 0;
    const int last_tag = tg[last_idx];
    const float score = numer_tot + lg[(SEQ - 1) * NTAGS + last_tag] * (float)mk[SEQ - 1];
    atomicAdd(out, score - log_den);
  }
}

extern "C" void kernel_launch(void* const* d_in, const int* in_sizes, int n_in,
                              void* d_out, int out_size, void* d_ws, size_t ws_size,
                              hipStream_t stream) {
  const float* logits = (const float*)d_in[0];
  const int*   tags   = (const int*)d_in[1];
  const int*   mask   = (const int*)d_in[2];
  const float* trans  = (const float*)d_in[3];
  float* out = (float*)d_out;

  hipMemsetAsync(out, 0, sizeof(float), stream);  // harness poisons d_out with 0xAA
  crf_fwd<<<dim3(BATCH), dim3(256), 0, stream>>>(logits, tags, mask, trans, out);
}

// Round 6
// 501.640 us; speedup vs baseline: 1.3093x; 1.3093x over previous
//
#include <hip/hip_runtime.h>
#include <stdint.h>

#define NTAGS 256
#define BATCH 64
#define SEQ   512
#define NTHREADS 1024   // 16 waves: thread (q=tid>>8, k=tid&255); q = quarter of j-range

#if __has_builtin(__builtin_amdgcn_fdot2_f32_bf16)
#define HAVE_DOT2_BF16 1
typedef __bf16 bf16x2_t __attribute__((ext_vector_type(2)));
#define BCAST(x) __builtin_bit_cast(bf16x2_t, (unsigned int)(x))
#endif

// ---------------- wave (64-lane) reductions ----------------
__device__ __forceinline__ float wave_max(float v) {
#pragma unroll
  for (int o = 32; o; o >>= 1) v = fmaxf(v, __shfl_xor(v, o));
  return v;
}
__device__ __forceinline__ float wave_sum(float v) {
#pragma unroll
  for (int o = 32; o; o >>= 1) v += __shfl_xor(v, o);
  return v;
}

// f32 -> bf16 bits, round-to-nearest-even
__device__ __forceinline__ unsigned int f32_to_bf16_bits(float f) {
  unsigned int u = __float_as_uint(f);
  return (u + 0x7FFFu + ((u >> 16) & 1u)) >> 16;
}

// 32 packed-bf16x2 ET words per thread (named locals). Rounds 1-4 proved the
// RA pins its VGPR budget at ~84 and spills any ~128-word array no matter what
// attributes are applied. 32 words + ~25 overhead < 84 -> resident by
// construction; the decomposition, not the allocator, guarantees it.
#define ET32(M) \
  M(0) M(1) M(2) M(3) M(4) M(5) M(6) M(7) \
  M(8) M(9) M(10) M(11) M(12) M(13) M(14) M(15) \
  M(16) M(17) M(18) M(19) M(20) M(21) M(22) M(23) \
  M(24) M(25) M(26) M(27) M(28) M(29) M(30) M(31)

#define ET_DECL(p) unsigned int et##p;
#define ET_INIT(p) \
  et##p = f32_to_bf16_bits(exp2f(trans[(64*q + 2*(p))      * NTAGS + k] * LOG2E)) | \
          (f32_to_bf16_bits(exp2f(trans[(64*q + 2*(p) + 1) * NTAGS + k] * LOG2E)) << 16);

// accumulator chain per step index: p % 4 (direct literal paste, no re-scan issue)
#define ACC(p) ACC_##p
#define ACC_0  acc0
#define ACC_1  acc1
#define ACC_2  acc2
#define ACC_3  acc3
#define ACC_4  acc0
#define ACC_5  acc1
#define ACC_6  acc2
#define ACC_7  acc3
#define ACC_8  acc0
#define ACC_9  acc1
#define ACC_10 acc2
#define ACC_11 acc3
#define ACC_12 acc0
#define ACC_13 acc1
#define ACC_14 acc2
#define ACC_15 acc3
#define ACC_16 acc0
#define ACC_17 acc1
#define ACC_18 acc2
#define ACC_19 acc3
#define ACC_20 acc0
#define ACC_21 acc1
#define ACC_22 acc2
#define ACC_23 acc3
#define ACC_24 acc0
#define ACC_25 acc1
#define ACC_26 acc2
#define ACC_27 acc3
#define ACC_28 acc0
#define ACC_29 acc1
#define ACC_30 acc2
#define ACC_31 acc3

#if HAVE_DOT2_BF16
#define DOT_STEP(p) { \
    int s_ = __builtin_amdgcn_readlane(w0, p); \
    ACC(p) = __builtin_amdgcn_fdot2_f32_bf16(BCAST(et##p), BCAST(s_), ACC(p), false); }
#else
#define DOT_STEP(p) { \
    unsigned int s_ = (unsigned int)__builtin_amdgcn_readlane(w0, p); \
    ACC(p) = fmaf(__uint_as_float(s_ << 16),         __uint_as_float(et##p << 16),         ACC(p)); \
    ACC(p) = fmaf(__uint_as_float(s_ & 0xFFFF0000u), __uint_as_float(et##p & 0xFFFF0000u), ACC(p)); }
#endif

// One block (16 waves, full CU) per batch element.
// Linear-domain forward: a <- (ET^T a) * exp(logit_t), exact pow2 renorm /4 steps.
// Thread (q,k): partial_qk = sum_{j in [64q,64q+64)} a_j * exp(T[j][k]);
// quarters combined through LDS; threads tid<256 do the epilogue.
__global__ __launch_bounds__(NTHREADS, 4)
void crf_fwd(const float* __restrict__ logits,
             const int*   __restrict__ tags,
             const int*   __restrict__ mask,
             const float* __restrict__ trans,
             float* __restrict__ out)
{
  const int b    = blockIdx.x;
  const int tid  = threadIdx.x;
  const int k    = tid & 255;
  const int q    = tid >> 8;        // wave-uniform (waves 0-3: q=0, 4-7: q=1, ...)
  const int lane = tid & 63;
  const int wid  = tid >> 6;        // 0..15

  __shared__ unsigned int abuf[2][NTAGS / 2];  // alpha, packed bf16x2, double-buffered
  __shared__ float part[4 * NTAGS];            // quarter partials
  __shared__ float red[4];
  __shared__ float rnum[16], rms[16];

  const float LOG2E = 1.4426950408889634f;
  const float LN2   = 0.6931471805599453f;

  const float* lg = logits + (size_t)b * SEQ * NTAGS;
  const int*   tg = tags + b * SEQ;
  const int*   mk = mask + b * SEQ;

  // ---------------- numerator (joint likelihood) ----------------
  float numer = 0.f, msum = 0.f;
  for (int t = tid; t < SEQ; t += NTHREADS) {
    int   tag_t = tg[t];
    float m_t   = (float)mk[t];
    msum += m_t;
    if (t < SEQ - 1) {
      numer += lg[t * NTAGS + tag_t] * m_t;                       // emit, mask[:, :-1]
      numer += trans[tag_t * NTAGS + tg[t + 1]] * (float)mk[t+1]; // trans, mask[:, 1:]
    }
  }
  numer = wave_sum(numer);
  msum  = wave_sum(msum);
  if (lane == 0) { rnum[wid] = numer; rms[wid] = msum; }
  __syncthreads();
  float numer_tot = 0.f, msum_tot = 0.f;
#pragma unroll
  for (int w = 0; w < 16; ++w) { numer_tot += rnum[w]; msum_tot += rms[w]; }
  __syncthreads();

  // ---------------- ET quarter-column -> 32 named registers ----------------
  ET32(ET_DECL)
  ET32(ET_INIT)

  // ---------------- init alpha at t=0 ----------------
  float mya = 0.f;
  int esum = 0;
  if (tid < 256) {
    mya = exp2f(lg[k] * LOG2E);
    ((unsigned short*)abuf[0])[k] = (unsigned short)f32_to_bf16_bits(mya);
  }
  __syncthreads();

  // prefetch logits/mask two steps ahead (epilogue threads only)
  float g0 = 0.f, g1 = 0.f;
  int   m0v = 1, m1v = 1;
  if (q == 0) {
    g0 = lg[1 * NTAGS + k];
    g1 = lg[2 * NTAGS + k];
    m0v = mk[1];
    m1v = mk[2];
  }

  int cur = 0;
  for (int t = 1; t < SEQ; ++t) {
    float g = 0.f; int m = 1;
    if (q == 0) {
      g = g0;  m = m0v;
      g0 = g1; m0v = m1v;
      const int tpre = (t + 2 <= SEQ - 1) ? (t + 2) : (SEQ - 1);
      g1 = lg[tpre * NTAGS + k];
      m1v = mk[tpre];
    }

    // lanes 0-31 hold this wave's 32 alpha pair-words; lanes 32-63 duplicate
    // (same-address broadcast read, conflict-free)
    const int w0 = (int)abuf[cur][(q << 5) + (lane & 31)];

    float acc0 = 0.f, acc1 = 0.f, acc2 = 0.f, acc3 = 0.f;
    ET32(DOT_STEP)   // 32x { v_readlane -> SGPR ; v_dot2_f32_bf16 }

    part[tid] = (acc0 + acc1) + (acc2 + acc3);
    __syncthreads();

    if (tid < 256) {
      const float s = (part[k] + part[NTAGS + k]) + (part[2 * NTAGS + k] + part[3 * NTAGS + k]);
      const float cand = s * exp2f(g * LOG2E);
      mya = m ? cand : mya;   // mask: freeze alpha when mask==0
    }

    if ((t & 3) == 3) {
      // exact power-of-2 renorm every 4 steps; exponent bookkeeping in esum
      if (tid < 256) {
        float mx = wave_max(mya);
        if (lane == 0) red[wid] = mx;   // wid 0..3 here
      }
      __syncthreads();
      if (tid < 256) {
        const float mx = fmaxf(fmaxf(red[0], red[1]), fmaxf(red[2], red[3]));
        const int e = (int)((__float_as_uint(mx) >> 23) & 0xFF) - 127;
        mya *= __uint_as_float((uint32_t)(127 - e) << 23);  // *2^-e, exact
        esum += e;
      }
    }

    cur ^= 1;
    if (tid < 256)
      ((unsigned short*)abuf[cur])[k] = (unsigned short)f32_to_bf16_bits(mya);
    __syncthreads();
  }

  // ---------------- log_den = log(sum_k a) + esum*ln2 ----------------
  if (tid < 256) {
    float ssum = wave_sum(mya);
    if (lane == 0) red[wid] = ssum;
  }
  __syncthreads();

  if (tid == 0) {
    const float ssum = (red[0] + red[1]) + (red[2] + red[3]);
    const float log_den = logf(ssum) + (float)esum * LN2;
    int last_idx = (int)msum_tot - 1;
    if (last_idx < 0) last_idx = 0;
    const int last_tag = tg[last_idx];
    const float score = numer_tot + lg[(SEQ - 1) * NTAGS + last_tag] * (float)mk[SEQ - 1];
    atomicAdd(out, score - log_den);
  }
}

extern "C" void kernel_launch(void* const* d_in, const int* in_sizes, int n_in,
                              void* d_out, int out_size, void* d_ws, size_t ws_size,
                              hipStream_t stream) {
  const float* logits = (const float*)d_in[0];
  const int*   tags   = (const int*)d_in[1];
  const int*   mask   = (const int*)d_in[2];
  const float* trans  = (const float*)d_in[3];
  float* out = (float*)d_out;

  hipMemsetAsync(out, 0, sizeof(float), stream);  // harness poisons d_out with 0xAA
  crf_fwd<<<dim3(BATCH), dim3(NTHREADS), 0, stream>>>(logits, tags, mask, trans, out);
}